// Round 1
// baseline (70.371 us; speedup 1.0000x reference)
//
#include <hip/hip_runtime.h>
#include <math.h>

#define TJ 32

// Fused kernel. Normalization is deferred via the affine expansion:
//   sum_b f^T D f = sc^2 * ( Q - 2*mn*L + 8*mn^2*S ),   f = (a - mn)*sc
// with Q = sum_{ij} d_ij * sum_b a[b,i]*a[b,j],  L = sum_{ij} d_ij * A_j,
// A_j = sum_b a[b,j],  S = 1^T D 1 (pure grid constant).
// So the O(N^2) loop needs no global min/max first -> single fused pass.
// Each block writes partial Q,L (double) to its own ws slot; the 4 blocks
// with blockIdx.y==0 also produce i-tile min/max partials. A tiny combine
// kernel finishes (separate launch => cross-XCD visibility guaranteed, no
// reliance on ws poison state; out[0] gets a plain store each replay).
__global__ __launch_bounds__(256) void pair_fused(const float* __restrict__ in,
                                                  double* __restrict__ Qpart,
                                                  double* __restrict__ Lpart,
                                                  float* __restrict__ mnpart,
                                                  float* __restrict__ mxpart) {
    const int t = threadIdx.x;
    __shared__ __align__(16) float vjs[TJ * 8];
    __shared__ float vjsum[TJ];

    // stage unnormalized j-tile: TJ pixels x 8 batches (one value per thread)
    const int j0 = blockIdx.y * TJ;
    {
        const int jj = t >> 3, b = t & 7;
        const float* s = in + b * 12288 + (j0 + jj) * 3;
        vjs[jj * 8 + b] = (fabsf(s[0]) + fabsf(s[1])) + fabsf(s[2]);
    }
    __syncthreads();
    if (t < TJ) {
        const float* v = &vjs[t * 8];
        vjsum[t] = ((v[0] + v[1]) + (v[2] + v[3])) + ((v[4] + v[5]) + (v[6] + v[7]));
    }

    // compute this thread's 4 consecutive i-pixels x 8 batches (unnormalized).
    // 12 floats per batch = 3 aligned float4 loads (input is L2/L3-resident).
    const int ibase = blockIdx.x * 1024 + t * 4;
    float vi[4][8];
    #pragma unroll
    for (int b = 0; b < 8; ++b) {
        const float4* q = (const float4*)(in + b * 12288 + ibase * 3);
        const float4 q0 = q[0], q1 = q[1], q2 = q[2];
        vi[0][b] = (fabsf(q0.x) + fabsf(q0.y)) + fabsf(q0.z);
        vi[1][b] = (fabsf(q0.w) + fabsf(q1.x)) + fabsf(q1.y);
        vi[2][b] = (fabsf(q1.z) + fabsf(q1.w)) + fabsf(q2.x);
        vi[3][b] = (fabsf(q2.y) + fabsf(q2.z)) + fabsf(q2.w);
    }
    __syncthreads();

    // geometry: all 4 i's share one grid row; the whole j-tile shares one row.
    const float fri = (float)(ibase >> 6);
    const float frj = (float)(j0 >> 6);
    const float fdr = fri - frj;
    const float r2 = fdr * fdr;                       // tile-constant
    const float dc0 = (float)(ibase & 63) - (float)(j0 & 63);
    float dcr[4] = {dc0, dc0 + 1.0f, dc0 + 2.0f, dc0 + 3.0f};
    float acc[4] = {0.f, 0.f, 0.f, 0.f};
    float lacc = 0.f;

    #pragma unroll 8
    for (int jj = 0; jj < TJ; ++jj) {
        const float4* vp = (const float4*)&vjs[jj * 8];
        const float4 a = vp[0];              // uniform LDS addr -> broadcast
        const float4 c = vp[1];
        const float aj = vjsum[jj];
        float dd[4];
        #pragma unroll
        for (int m = 0; m < 4; ++m) {
            dd[m] = __builtin_amdgcn_sqrtf(fmaf(dcr[m], dcr[m], r2));
            dcr[m] -= 1.0f;
        }
        lacc = fmaf(aj, (dd[0] + dd[1]) + (dd[2] + dd[3]), lacc);
        #pragma unroll
        for (int m = 0; m < 4; ++m) {
            float dot = vi[m][0] * a.x;
            dot = fmaf(vi[m][1], a.y, dot);
            dot = fmaf(vi[m][2], a.z, dot);
            dot = fmaf(vi[m][3], a.w, dot);
            dot = fmaf(vi[m][4], c.x, dot);
            dot = fmaf(vi[m][5], c.y, dot);
            dot = fmaf(vi[m][6], c.z, dot);
            dot = fmaf(vi[m][7], c.w, dot);
            acc[m] = fmaf(dd[m], dot, acc[m]);
        }
    }

    // block-reduce Q and L in double, one ws slot per block
    double qd = (double)((acc[0] + acc[1]) + (acc[2] + acc[3]));
    double ld = (double)lacc;
    #pragma unroll
    for (int off = 32; off > 0; off >>= 1) {
        qd += __shfl_down(qd, off);
        ld += __shfl_down(ld, off);
    }
    __shared__ double sq[4], sl[4];
    if ((t & 63) == 0) { sq[t >> 6] = qd; sl[t >> 6] = ld; }
    __syncthreads();
    if (t == 0) {
        const int bid = blockIdx.y * 4 + blockIdx.x;
        Qpart[bid] = (sq[0] + sq[1]) + (sq[2] + sq[3]);
        Lpart[bid] = (sl[0] + sl[1]) + (sl[2] + sl[3]);
    }

    // min/max partials: the 4 blocks with by==0 jointly cover all 32768 values
    if (blockIdx.y == 0) {
        float mn = vi[0][0], mx = vi[0][0];
        #pragma unroll
        for (int m = 0; m < 4; ++m)
            #pragma unroll
            for (int b = 0; b < 8; ++b) {
                mn = fminf(mn, vi[m][b]);
                mx = fmaxf(mx, vi[m][b]);
            }
        #pragma unroll
        for (int off = 32; off > 0; off >>= 1) {
            mn = fminf(mn, __shfl_down(mn, off));
            mx = fmaxf(mx, __shfl_down(mx, off));
        }
        __shared__ float smn[4], smx[4];
        if ((t & 63) == 0) { smn[t >> 6] = mn; smx[t >> 6] = mx; }
        __syncthreads();
        if (t == 0) {
            mnpart[blockIdx.x] = fminf(fminf(smn[0], smn[1]), fminf(smn[2], smn[3]));
            mxpart[blockIdx.x] = fmaxf(fmaxf(smx[0], smx[1]), fmaxf(smx[2], smx[3]));
        }
    }
}

// Tiny finisher: reduce 512 double partials, compute S = 1^T D 1 in closed
// form (127x127 displacement bins), apply the affine-expansion combine, and
// plain-store the scalar (no atomics on out, no zero-init dependency).
__global__ __launch_bounds__(256) void combine_kernel(const double* __restrict__ Qpart,
                                                      const double* __restrict__ Lpart,
                                                      const float* __restrict__ mnpart,
                                                      const float* __restrict__ mxpart,
                                                      float* __restrict__ out) {
    const int t = threadIdx.x;
    double q = Qpart[t] + Qpart[t + 256];
    double l = Lpart[t] + Lpart[t + 256];
    double s = 0.0;
    for (int idx = t; idx < 127 * 127; idx += 256) {
        const int dx = idx / 127 - 63;
        const int dy = idx % 127 - 63;
        const float d = sqrtf((float)(dx * dx + dy * dy));
        s += (double)((64 - abs(dx)) * (64 - abs(dy))) * (double)d;
    }
    #pragma unroll
    for (int off = 32; off > 0; off >>= 1) {
        q += __shfl_down(q, off);
        l += __shfl_down(l, off);
        s += __shfl_down(s, off);
    }
    __shared__ double rq[4], rl[4], rs[4];
    if ((t & 63) == 0) { rq[t >> 6] = q; rl[t >> 6] = l; rs[t >> 6] = s; }
    __syncthreads();
    if (t == 0) {
        q = (rq[0] + rq[1]) + (rq[2] + rq[3]);
        l = (rl[0] + rl[1]) + (rl[2] + rl[3]);
        s = (rs[0] + rs[1]) + (rs[2] + rs[3]);
        const double mn = (double)fminf(fminf(mnpart[0], mnpart[1]),
                                        fminf(mnpart[2], mnpart[3]));
        const double mx = (double)fmaxf(fmaxf(mxpart[0], mxpart[1]),
                                        fmaxf(mxpart[2], mxpart[3]));
        const double sc = 1.0 / (mx - mn);
        const double tot = (q - 2.0 * mn * l + 8.0 * mn * mn * s) * sc * sc
                         * (1.0 / 134217728.0);     // /(B*N*N) = /2^27
        out[0] = (float)tot;
    }
}

extern "C" void kernel_launch(void* const* d_in, const int* in_sizes, int n_in,
                              void* d_out, int out_size, void* d_ws, size_t ws_size,
                              hipStream_t stream) {
    const float* in = (const float*)d_in[0];
    float* out = (float*)d_out;
    double* Qpart = (double*)d_ws;          // 512 doubles
    double* Lpart = Qpart + 512;            // 512 doubles
    float* mnpart = (float*)(Lpart + 512);  // 4 floats
    float* mxpart = mnpart + 4;             // 4 floats
    pair_fused<<<dim3(4, 128), dim3(256), 0, stream>>>(in, Qpart, Lpart, mnpart, mxpart);
    combine_kernel<<<dim3(1), dim3(256), 0, stream>>>(Qpart, Lpart, mnpart, mxpart, out);
    (void)in_sizes; (void)n_in; (void)out_size; (void)ws_size;
}

// Round 2
// 68.607 us; speedup vs baseline: 1.0257x; 1.0257x over previous
//
#include <hip/hip_runtime.h>
#include <math.h>

#define TJ 32

// Single fused kernel. Normalization deferred via affine expansion:
//   sum_b f^T D f = sc^2 * ( Q - 2*mn*L + 8*mn^2*S ),   f = (a - mn)*sc
// Q = sum_{ij} d_ij sum_b a[b,i]a[b,j],  L = sum_{ij} d_ij A_j,  A_j = sum_b a[b,j],
// S = 1^T D 1 -- a pure grid constant, computed ON HOST and passed as an arg.
// Last-block-done pattern replaces the combine launch: blocks publish partials
// with AGENT-scope atomic stores + device fence, take a uint ticket, and the
// 512th block reduces everything and plain-stores out[0] (no out-poison
// dependency). Ticket starts at ws poison 0xAAAAAAAA (0 also accepted).
__global__ __launch_bounds__(256) void fused_all(const float* __restrict__ in,
                                                 double* __restrict__ Qpart,
                                                 double* __restrict__ Lpart,
                                                 float* __restrict__ mnpart,
                                                 float* __restrict__ mxpart,
                                                 unsigned* __restrict__ ticket,
                                                 float* __restrict__ out,
                                                 double Sconst) {
    const int t = threadIdx.x;
    __shared__ __align__(16) float vjs[TJ * 8];
    __shared__ float vjsum[TJ];
    __shared__ double sq[4], sl[4];
    __shared__ float smn[4], smx[4];
    __shared__ int is_last;

    // stage unnormalized j-tile: TJ pixels x 8 batches (one value per thread)
    const int j0 = blockIdx.y * TJ;
    {
        const int jj = t >> 3, b = t & 7;
        const float* s = in + b * 12288 + (j0 + jj) * 3;
        vjs[jj * 8 + b] = (fabsf(s[0]) + fabsf(s[1])) + fabsf(s[2]);
    }
    __syncthreads();
    if (t < TJ) {
        const float* v = &vjs[t * 8];
        vjsum[t] = ((v[0] + v[1]) + (v[2] + v[3])) + ((v[4] + v[5]) + (v[6] + v[7]));
    }

    // this thread's 4 consecutive i-pixels x 8 batches (unnormalized).
    const int ibase = blockIdx.x * 1024 + t * 4;
    float vi[4][8];
    #pragma unroll
    for (int b = 0; b < 8; ++b) {
        const float4* q = (const float4*)(in + b * 12288 + ibase * 3);
        const float4 q0 = q[0], q1 = q[1], q2 = q[2];
        vi[0][b] = (fabsf(q0.x) + fabsf(q0.y)) + fabsf(q0.z);
        vi[1][b] = (fabsf(q0.w) + fabsf(q1.x)) + fabsf(q1.y);
        vi[2][b] = (fabsf(q1.z) + fabsf(q1.w)) + fabsf(q2.x);
        vi[3][b] = (fabsf(q2.y) + fabsf(q2.z)) + fabsf(q2.w);
    }
    __syncthreads();

    // geometry: 4 i's share one grid row; the whole j-tile shares one row.
    const float fri = (float)(ibase >> 6);
    const float frj = (float)(j0 >> 6);
    const float fdr = fri - frj;
    const float r2 = fdr * fdr;                       // tile-constant
    const float dc0 = (float)(ibase & 63) - (float)(j0 & 63);
    float dcr[4] = {dc0, dc0 + 1.0f, dc0 + 2.0f, dc0 + 3.0f};
    float acc[4] = {0.f, 0.f, 0.f, 0.f};
    float lacc = 0.f;

    #pragma unroll 8
    for (int jj = 0; jj < TJ; ++jj) {
        const float4* vp = (const float4*)&vjs[jj * 8];
        const float4 a = vp[0];              // uniform LDS addr -> broadcast
        const float4 c = vp[1];
        const float aj = vjsum[jj];
        float dd[4];
        #pragma unroll
        for (int m = 0; m < 4; ++m) {
            dd[m] = __builtin_amdgcn_sqrtf(fmaf(dcr[m], dcr[m], r2));
            dcr[m] -= 1.0f;
        }
        lacc = fmaf(aj, (dd[0] + dd[1]) + (dd[2] + dd[3]), lacc);
        #pragma unroll
        for (int m = 0; m < 4; ++m) {
            float dot = vi[m][0] * a.x;
            dot = fmaf(vi[m][1], a.y, dot);
            dot = fmaf(vi[m][2], a.z, dot);
            dot = fmaf(vi[m][3], a.w, dot);
            dot = fmaf(vi[m][4], c.x, dot);
            dot = fmaf(vi[m][5], c.y, dot);
            dot = fmaf(vi[m][6], c.z, dot);
            dot = fmaf(vi[m][7], c.w, dot);
            acc[m] = fmaf(dd[m], dot, acc[m]);
        }
    }

    // per-thread min/max over its 32 unnormalized values
    float mnv = vi[0][0], mxv = vi[0][0];
    #pragma unroll
    for (int m = 0; m < 4; ++m)
        #pragma unroll
        for (int b = 0; b < 8; ++b) {
            mnv = fminf(mnv, vi[m][b]);
            mxv = fmaxf(mxv, vi[m][b]);
        }

    // block-reduce Q, L (double) and min/max; publish one partial per block
    double qd = (double)((acc[0] + acc[1]) + (acc[2] + acc[3]));
    double ld = (double)lacc;
    #pragma unroll
    for (int off = 32; off > 0; off >>= 1) {
        qd += __shfl_down(qd, off);
        ld += __shfl_down(ld, off);
        mnv = fminf(mnv, __shfl_down(mnv, off));
        mxv = fmaxf(mxv, __shfl_down(mxv, off));
    }
    if ((t & 63) == 0) {
        const int w = t >> 6;
        sq[w] = qd; sl[w] = ld; smn[w] = mnv; smx[w] = mxv;
    }
    __syncthreads();
    const int bid = blockIdx.y * 4 + blockIdx.x;
    if (t == 0) {
        __hip_atomic_store(&Qpart[bid], (sq[0] + sq[1]) + (sq[2] + sq[3]),
                           __ATOMIC_RELAXED, __HIP_MEMORY_SCOPE_AGENT);
        __hip_atomic_store(&Lpart[bid], (sl[0] + sl[1]) + (sl[2] + sl[3]),
                           __ATOMIC_RELAXED, __HIP_MEMORY_SCOPE_AGENT);
        __hip_atomic_store(&mnpart[bid], fminf(fminf(smn[0], smn[1]), fminf(smn[2], smn[3])),
                           __ATOMIC_RELAXED, __HIP_MEMORY_SCOPE_AGENT);
        __hip_atomic_store(&mxpart[bid], fmaxf(fmaxf(smx[0], smx[1]), fmaxf(smx[2], smx[3])),
                           __ATOMIC_RELAXED, __HIP_MEMORY_SCOPE_AGENT);
        __threadfence();
        const unsigned old = atomicAdd(ticket, 1u);
        // ws is poisoned 0xAA each replay; also accept a zeroed ws.
        is_last = (old == 0xAAAAAAAAu + 511u) || (old == 511u);
    }
    __syncthreads();
    if (!is_last) return;

    // === last block: global combine ===
    __threadfence();
    double q  = __hip_atomic_load(&Qpart[t],       __ATOMIC_RELAXED, __HIP_MEMORY_SCOPE_AGENT)
              + __hip_atomic_load(&Qpart[t + 256], __ATOMIC_RELAXED, __HIP_MEMORY_SCOPE_AGENT);
    double l  = __hip_atomic_load(&Lpart[t],       __ATOMIC_RELAXED, __HIP_MEMORY_SCOPE_AGENT)
              + __hip_atomic_load(&Lpart[t + 256], __ATOMIC_RELAXED, __HIP_MEMORY_SCOPE_AGENT);
    float mn2 = fminf(__hip_atomic_load(&mnpart[t],       __ATOMIC_RELAXED, __HIP_MEMORY_SCOPE_AGENT),
                      __hip_atomic_load(&mnpart[t + 256], __ATOMIC_RELAXED, __HIP_MEMORY_SCOPE_AGENT));
    float mx2 = fmaxf(__hip_atomic_load(&mxpart[t],       __ATOMIC_RELAXED, __HIP_MEMORY_SCOPE_AGENT),
                      __hip_atomic_load(&mxpart[t + 256], __ATOMIC_RELAXED, __HIP_MEMORY_SCOPE_AGENT));
    #pragma unroll
    for (int off = 32; off > 0; off >>= 1) {
        q += __shfl_down(q, off);
        l += __shfl_down(l, off);
        mn2 = fminf(mn2, __shfl_down(mn2, off));
        mx2 = fmaxf(mx2, __shfl_down(mx2, off));
    }
    if ((t & 63) == 0) {
        const int w = t >> 6;
        sq[w] = q; sl[w] = l; smn[w] = mn2; smx[w] = mx2;
    }
    __syncthreads();
    if (t == 0) {
        q = (sq[0] + sq[1]) + (sq[2] + sq[3]);
        l = (sl[0] + sl[1]) + (sl[2] + sl[3]);
        const double mn = (double)fminf(fminf(smn[0], smn[1]), fminf(smn[2], smn[3]));
        const double mx = (double)fmaxf(fmaxf(smx[0], smx[1]), fmaxf(smx[2], smx[3]));
        const double sc = 1.0 / (mx - mn);
        const double tot = (q - 2.0 * mn * l + 8.0 * mn * mn * Sconst) * sc * sc
                         * (1.0 / 134217728.0);     // /(B*N*N) = /2^27
        out[0] = (float)tot;                        // plain store
    }
}

// S = 1^T D 1 over the 64x64 grid, by displacement bins -- pure constant,
// computed once on the HOST (no GPU time, graph-capture safe).
static double compute_S() {
    double s = 0.0;
    for (int dx = -63; dx <= 63; ++dx)
        for (int dy = -63; dy <= 63; ++dy)
            s += (double)((64 - (dx < 0 ? -dx : dx)) * (64 - (dy < 0 ? -dy : dy)))
               * sqrt((double)(dx * dx + dy * dy));
    return s;
}

extern "C" void kernel_launch(void* const* d_in, const int* in_sizes, int n_in,
                              void* d_out, int out_size, void* d_ws, size_t ws_size,
                              hipStream_t stream) {
    static const double S = compute_S();     // host-side, once per process
    const float* in = (const float*)d_in[0];
    float* out = (float*)d_out;
    double* Qpart = (double*)d_ws;           // 512 doubles
    double* Lpart = Qpart + 512;             // 512 doubles
    float* mnpart = (float*)(Lpart + 512);   // 512 floats
    float* mxpart = mnpart + 512;            // 512 floats
    unsigned* ticket = (unsigned*)(mxpart + 512);
    fused_all<<<dim3(4, 128), dim3(256), 0, stream>>>(in, Qpart, Lpart, mnpart,
                                                      mxpart, ticket, out, S);
    (void)in_sizes; (void)n_in; (void)out_size; (void)ws_size;
}

// Round 3
// 62.316 us; speedup vs baseline: 1.1293x; 1.1010x over previous
//
#include <hip/hip_runtime.h>
#include <math.h>

#define TJ 32

// Kernel 1: a[b,p] = sum_c |in[b,p,c]|, stored transposed Ft[p*8+b];
// per-block min/max partials; zero the output scalar.
__global__ __launch_bounds__(256) void prep_kernel(const float* __restrict__ in,
                                                   float* __restrict__ Ft,
                                                   float* __restrict__ bmin,
                                                   float* __restrict__ bmax,
                                                   float* __restrict__ out) {
    const int t = threadIdx.x;
    const int g = blockIdx.x * 256 + t;      // 0..32767
    const int b = g >> 12;                   // batch 0..7
    const int p = g & 4095;                  // pixel 0..4095
    const float* s = in + b * 12288 + p * 3;
    const float v = fabsf(s[0]) + fabsf(s[1]) + fabsf(s[2]);
    Ft[p * 8 + b] = v;

    float mn = v, mx = v;
    #pragma unroll
    for (int off = 32; off > 0; off >>= 1) {
        mn = fminf(mn, __shfl_down(mn, off));
        mx = fmaxf(mx, __shfl_down(mx, off));
    }
    __shared__ float smn[4], smx[4];
    if ((t & 63) == 0) { smn[t >> 6] = mn; smx[t >> 6] = mx; }
    __syncthreads();
    if (t == 0) {
        mn = fminf(fminf(smn[0], smn[1]), fminf(smn[2], smn[3]));
        mx = fmaxf(fmaxf(smx[0], smx[1]), fmaxf(smx[2], smx[3]));
        bmin[blockIdx.x] = mn;
        bmax[blockIdx.x] = mx;
        if (blockIdx.x == 0) out[0] = 0.0f;   // d_out is poisoned 0xAA each replay
    }
}

// Kernel 2: sum over pairs, TRIANGULAR tile grid exploiting d/g symmetry.
// i-tiles of 1024 (x=0..3), j-tiles of TJ=32 (by=0..127). Block (x,by) exists
// only for by >= 32x: the 32 j-tiles inside the i-tile's own span form the
// fully-symmetric diagonal sub-block (weight 1, computed whole); j-tiles
// strictly beyond it are each the (i<j) member of a mirrored pair (weight 2);
// by < 32x dropped. 320 blocks instead of 512 (-37.5% work), identical inner
// loop. Each thread owns 4 consecutive i's (one grid row); the whole j-tile
// lies in one row too (32 | 64), so dr^2 is a per-thread constant and column
// deltas are maintained by -1.0 decrements. sqrt = raw v_sqrt_f32.
__global__ __launch_bounds__(256) void pair_kernel(const float* __restrict__ Ft,
                                                   const float* __restrict__ bmin,
                                                   const float* __restrict__ bmax,
                                                   float* __restrict__ out) {
    const int t = threadIdx.x;
    // decode triangular block id -> (x, by)
    const int k = blockIdx.x;
    int x, by;
    if (k < 128)      { x = 0; by = k; }
    else if (k < 224) { x = 1; by = k - 128 + 32; }
    else if (k < 288) { x = 2; by = k - 224 + 64; }
    else              { x = 3; by = k - 288 + 96; }
    const float wgt = (by >= x * 32 + 32) ? 2.0f : 1.0f;

    __shared__ float s_mn, s_sc;
    __shared__ __align__(16) float vjs[TJ * 8];

    // reduce the 128 per-block min/max partials (wave 0 only)
    if (t < 64) {
        float mn = fminf(bmin[t], bmin[t + 64]);
        float mx = fmaxf(bmax[t], bmax[t + 64]);
        #pragma unroll
        for (int off = 32; off > 0; off >>= 1) {
            mn = fminf(mn, __shfl_down(mn, off));
            mx = fmaxf(mx, __shfl_down(mx, off));
        }
        if (t == 0) { s_mn = mn; s_sc = 1.0f / (mx - mn); }
    }
    __syncthreads();
    const float mn = s_mn, sc = s_sc;

    // stage normalized j-tile: TJ*8 = 256 floats, one per thread (coalesced)
    const int j0 = by * TJ;
    vjs[t] = (Ft[j0 * 8 + t] - mn) * sc;

    // load + normalize this thread's 4 V_i vectors (128B contiguous per lane)
    const int ibase = x * 1024 + t * 4;
    float vi[4][8];
    const float4* fv = (const float4*)(Ft + (size_t)ibase * 8);
    #pragma unroll
    for (int m = 0; m < 4; ++m) {
        float4 q0 = fv[m * 2 + 0];
        float4 q1 = fv[m * 2 + 1];
        vi[m][0] = (q0.x - mn) * sc; vi[m][1] = (q0.y - mn) * sc;
        vi[m][2] = (q0.z - mn) * sc; vi[m][3] = (q0.w - mn) * sc;
        vi[m][4] = (q1.x - mn) * sc; vi[m][5] = (q1.y - mn) * sc;
        vi[m][6] = (q1.z - mn) * sc; vi[m][7] = (q1.w - mn) * sc;
    }
    __syncthreads();

    // geometry: all 4 i's share one row; all TJ j's share one row.
    const float fri = (float)(ibase >> 6);
    const float frj = (float)(j0 >> 6);
    const float fdr = fri - frj;
    const float r2 = fdr * fdr;                       // tile-constant
    const float dc0 = (float)(ibase & 63) - (float)(j0 & 63);
    float dcr[4] = {dc0, dc0 + 1.0f, dc0 + 2.0f, dc0 + 3.0f};
    float acc[4] = {0.f, 0.f, 0.f, 0.f};

    #pragma unroll 8
    for (int jj = 0; jj < TJ; ++jj) {
        const float4* vp = (const float4*)&vjs[jj * 8];
        const float4 a = vp[0];              // uniform LDS addr -> broadcast
        const float4 c = vp[1];
        #pragma unroll
        for (int m = 0; m < 4; ++m) {
            const float d = __builtin_amdgcn_sqrtf(fmaf(dcr[m], dcr[m], r2));
            float dot = vi[m][0] * a.x;
            dot = fmaf(vi[m][1], a.y, dot);
            dot = fmaf(vi[m][2], a.z, dot);
            dot = fmaf(vi[m][3], a.w, dot);
            dot = fmaf(vi[m][4], c.x, dot);
            dot = fmaf(vi[m][5], c.y, dot);
            dot = fmaf(vi[m][6], c.z, dot);
            dot = fmaf(vi[m][7], c.w, dot);
            acc[m] = fmaf(d, dot, acc[m]);
            dcr[m] -= 1.0f;
        }
    }

    float r = (acc[0] + acc[1]) + (acc[2] + acc[3]);
    #pragma unroll
    for (int off = 32; off > 0; off >>= 1) r += __shfl_down(r, off);
    __shared__ float sacc[4];
    if ((t & 63) == 0) sacc[t >> 6] = r;
    __syncthreads();
    if (t == 0) {
        const float tot = (sacc[0] + sacc[1]) + (sacc[2] + sacc[3]);
        atomicAdd(out, tot * (wgt / 134217728.0f));   // /(B*N*N) = /2^27
    }
}

extern "C" void kernel_launch(void* const* d_in, const int* in_sizes, int n_in,
                              void* d_out, int out_size, void* d_ws, size_t ws_size,
                              hipStream_t stream) {
    const float* in = (const float*)d_in[0];
    float* out = (float*)d_out;
    float* Ft   = (float*)d_ws;          // 32768 floats (128 KiB)
    float* bmin = Ft + 32768;            // 128 floats
    float* bmax = bmin + 128;            // 128 floats
    prep_kernel<<<dim3(128), dim3(256), 0, stream>>>(in, Ft, bmin, bmax, out);
    pair_kernel<<<dim3(320), dim3(256), 0, stream>>>(Ft, bmin, bmax, out);
    (void)in_sizes; (void)n_in; (void)out_size; (void)ws_size;
}